// Round 8
// baseline (391.609 us; speedup 1.0000x reference)
//
#include <hip/hip_runtime.h>
#include <hip/hip_fp16.h>

constexpr int B = 2, H = 12, S = 2048, D = 64;
constexpr int TQ = 16;            // query rows per block
constexpr int NBLK_Q = S / TQ;    // 128
constexpr size_t BHSD = (size_t)B * H * S * D;   // 3,145,728

using f16x8 = _Float16 __attribute__((ext_vector_type(8)));
using f16x4 = _Float16 __attribute__((ext_vector_type(4)));
using f32x4 = float   __attribute__((ext_vector_type(4)));

// score swizzle: XOR element-index bits 3-5 with ((k>>6) ^ q). 4/8-granule preserving.
__device__ __forceinline__ int swz2(int q, int k) {
    return k ^ ((((k >> 6) ^ q) & 7) << 3);
}

// ---- pre-pass: K fp32 [bh][key][d] -> f16 MFMA-tiled ----
// Kh element index: t*1024 + c2*512 + (grp*16+row)*8 + e ; key=t*16+row, d=c2*32+grp*8+e
__global__ __launch_bounds__(256)
void cvt_k_kernel(const float* __restrict__ K, _Float16* __restrict__ Kh) {
    const int bh   = blockIdx.x >> 6;
    const int t    = (blockIdx.x & 63) * 2 + (threadIdx.x >> 7);
    const int f    = threadIdx.x & 127;           // c2*64 + grp*16 + row
    const int c2   = f >> 6, grp = (f >> 4) & 3, row = f & 15;
    const size_t bhSD = (size_t)bh * S * D;
    const float* src = K + bhSD + (size_t)(t * 16 + row) * D + c2 * 32 + grp * 8;
    const float4 x0 = *reinterpret_cast<const float4*>(src);
    const float4 x1 = *reinterpret_cast<const float4*>(src + 4);
    f16x8 y;
    y[0] = (_Float16)x0.x; y[1] = (_Float16)x0.y; y[2] = (_Float16)x0.z; y[3] = (_Float16)x0.w;
    y[4] = (_Float16)x1.x; y[5] = (_Float16)x1.y; y[6] = (_Float16)x1.z; y[7] = (_Float16)x1.w;
    *reinterpret_cast<f16x8*>(Kh + bhSD + (size_t)t * 1024 + f * 8) = y;
}

// ---- pre-pass: V fp32 [bh][k][d] -> f16 MFMA-tiled transposed ----
// Vt element index: c*2048 + dh*1024 + n2*512 + (grp*16+row)*8 + e ; d=dh*32+n2*16+row, k=c*32+grp*8+e
__global__ __launch_bounds__(256)
void tr_v_kernel(const float* __restrict__ V, _Float16* __restrict__ Vt) {
    const int bh = blockIdx.x >> 6;
    const int c  = blockIdx.x & 63;
    const int f  = threadIdx.x;                   // dh*128 + n2*64 + grp*16 + row
    const int dh = f >> 7, n2 = (f >> 6) & 1, grp = (f >> 4) & 3, row = f & 15;
    const int d  = dh * 32 + n2 * 16 + row;
    const size_t bhSD = (size_t)bh * S * D;
    const float* src = V + bhSD + (size_t)(c * 32 + grp * 8) * D + d;
    f16x8 y;
    #pragma unroll
    for (int e = 0; e < 8; ++e) y[e] = (_Float16)src[e * D];
    *reinterpret_cast<f16x8*>(Vt + bhSD + (size_t)c * 2048 + f * 8) = y;
}

// ---------------- main fused kernel: 1024 threads / 16 waves, 2 blocks/CU ----------------
template <bool PRE>
__global__ __launch_bounds__(1024, 8)
void sparsemax_attn_kernel(const float* __restrict__ Q, const float* __restrict__ K,
                           const float* __restrict__ V, const float* __restrict__ mask,
                           const float* __restrict__ scale, float* __restrict__ out,
                           const _Float16* __restrict__ Kh, const _Float16* __restrict__ Vt)
{
    __shared__ alignas(16) _Float16 s_sh[TQ * 2048];      // 64 KB scores [q][k-swz]
    __shared__ alignas(16) float    madd_sh[S];           // 8 KB mask additive terms
    __shared__ alignas(16) float    red_sh[TQ][68];       // 4.25 KB output accumulators (padded)
    __shared__ float tau_s[TQ];

    const int tid  = threadIdx.x;
    const int lane = tid & 63;
    const int w    = tid >> 6;              // wave 0..15
    const int row  = lane & 15;
    const int grp  = lane >> 4;             // 0..3
    const int bh   = blockIdx.x / NBLK_Q;
    const int qt   = blockIdx.x - bh * NBLK_Q;
    const int b    = bh / H;
    const int h    = bh - b * H;
    const int q0   = qt * TQ;

    const size_t bhSD = (size_t)bh * S * D;
    const float* mrow = mask + (size_t)b * S;
    const float  sc   = __expf(scale[h]) * 0.125f;

    // mask -> LDS additive terms; zero the output accumulators
    madd_sh[tid]        = (1.0f - mrow[tid])        * -1.0e9f;
    madd_sh[tid + 1024] = (1.0f - mrow[tid + 1024]) * -1.0e9f;
    reinterpret_cast<float*>(red_sh)[tid] = 0.0f;
    if (tid < TQ * 68 - 1024) reinterpret_cast<float*>(red_sh)[1024 + tid] = 0.0f;

    // ---- Q fragments, sc folded in: qa[c][j] = Q[q0+row][c*32+grp*8+j] * sc ----
    f16x8 qa[2];
    {
        const float* qr = Q + bhSD + (size_t)(q0 + row) * D + grp * 8;
        #pragma unroll
        for (int c = 0; c < 2; ++c) {
            const float4 x0 = *reinterpret_cast<const float4*>(qr + c * 32);
            const float4 x1 = *reinterpret_cast<const float4*>(qr + c * 32 + 4);
            qa[c][0] = (_Float16)(x0.x * sc); qa[c][1] = (_Float16)(x0.y * sc);
            qa[c][2] = (_Float16)(x0.z * sc); qa[c][3] = (_Float16)(x0.w * sc);
            qa[c][4] = (_Float16)(x1.x * sc); qa[c][5] = (_Float16)(x1.y * sc);
            qa[c][6] = (_Float16)(x1.z * sc); qa[c][7] = (_Float16)(x1.w * sc);
        }
    }
    __syncthreads();   // madd + red init visible

    // ---------------- Phase 1: S^T tiles via mfma(K, Q) -> [q][k] LDS ----------------
    if constexpr (PRE) {
        const _Float16* ksrc = Kh + bhSD + (size_t)(w * 8) * 1024 + lane * 8;
        f16x8 ka0 = *reinterpret_cast<const f16x8*>(ksrc);
        f16x8 ka1 = *reinterpret_cast<const f16x8*>(ksrc + 512);
        #pragma unroll
        for (int i = 0; i < 8; ++i) {
            f16x8 nb0, nb1;
            if (i < 7) {
                nb0 = *reinterpret_cast<const f16x8*>(ksrc + (i + 1) * 1024);
                nb1 = *reinterpret_cast<const f16x8*>(ksrc + (i + 1) * 1024 + 512);
            }
            f32x4 acc = {0.f, 0.f, 0.f, 0.f};
            acc = __builtin_amdgcn_mfma_f32_16x16x32_f16(ka0, qa[0], acc, 0, 0, 0);
            acc = __builtin_amdgcn_mfma_f32_16x16x32_f16(ka1, qa[1], acc, 0, 0, 0);
            const int key0 = (w * 8 + i) * 16;
            const float4 ma = *reinterpret_cast<const float4*>(madd_sh + key0 + grp * 4);
            f16x4 st;
            #pragma unroll
            for (int r = 0; r < 4; ++r)
                st[r] = (_Float16)fmaxf(acc[r] + (&ma.x)[r], -60000.0f);
            *reinterpret_cast<f16x4*>(&s_sh[row * 2048 + swz2(row, key0 + grp * 4)]) = st;
            ka0 = nb0; ka1 = nb1;
        }
    } else {
        for (int t = w * 8; t < w * 8 + 8; ++t) {
            const int key0 = t * 16;
            const float* kp = K + bhSD + (size_t)(key0 + row) * D + grp * 8;
            f16x8 kb0, kb1;
            #pragma unroll
            for (int c = 0; c < 2; ++c) {
                const float4 x0 = *reinterpret_cast<const float4*>(kp + c * 32);
                const float4 x1 = *reinterpret_cast<const float4*>(kp + c * 32 + 4);
                f16x8& kb = c ? kb1 : kb0;
                kb[0] = (_Float16)x0.x; kb[1] = (_Float16)x0.y;
                kb[2] = (_Float16)x0.z; kb[3] = (_Float16)x0.w;
                kb[4] = (_Float16)x1.x; kb[5] = (_Float16)x1.y;
                kb[6] = (_Float16)x1.z; kb[7] = (_Float16)x1.w;
            }
            f32x4 acc = {0.f, 0.f, 0.f, 0.f};
            acc = __builtin_amdgcn_mfma_f32_16x16x32_f16(kb0, qa[0], acc, 0, 0, 0);
            acc = __builtin_amdgcn_mfma_f32_16x16x32_f16(kb1, qa[1], acc, 0, 0, 0);
            const float4 ma = *reinterpret_cast<const float4*>(madd_sh + key0 + grp * 4);
            f16x4 st;
            #pragma unroll
            for (int r = 0; r < 4; ++r)
                st[r] = (_Float16)fmaxf(acc[r] + (&ma.x)[r], -60000.0f);
            *reinterpret_cast<f16x4*>(&s_sh[row * 2048 + swz2(row, key0 + grp * 4)]) = st;
        }
    }
    __syncthreads();

    // ---------------- Phase 2: tau for row q=w — f16-register resident, no spill ------
    {
        const _Float16* zrow = &s_sh[w * 2048];
        const f16x8 zv0 = *reinterpret_cast<const f16x8*>(&zrow[swz2(w, lane * 32 +  0)]);
        const f16x8 zv1 = *reinterpret_cast<const f16x8*>(&zrow[swz2(w, lane * 32 +  8)]);
        const f16x8 zv2 = *reinterpret_cast<const f16x8*>(&zrow[swz2(w, lane * 32 + 16)]);
        const f16x8 zv3 = *reinterpret_cast<const f16x8*>(&zrow[swz2(w, lane * 32 + 24)]);
        // per-lane max via packed f16
        const f16x8 m8 = __builtin_elementwise_max(__builtin_elementwise_max(zv0, zv1),
                                                   __builtin_elementwise_max(zv2, zv3));
        float m = (float)m8[0];
        #pragma unroll
        for (int e = 1; e < 8; ++e) m = fmaxf(m, (float)m8[e]);
        #pragma unroll
        for (int off = 32; off >= 1; off >>= 1) m = fmaxf(m, __shfl_xor(m, off));
        const float thr = m - 1.0f;          // tau* >= max-1
        float c0 = -1.0e30f, c1 = -1.0e30f, c2 = -1.0e30f;
        int lc = 0;
#define EXTRACT8(ZV) { _Pragma("unroll") for (int e = 0; e < 8; ++e) { \
            const float zz = (float)(ZV)[e]; \
            if (zz > thr) { \
                c2 = (lc == 2) ? zz : c2; \
                c1 = (lc == 1) ? zz : c1; \
                c0 = (lc == 0) ? zz : c0; \
                ++lc; } } }
        EXTRACT8(zv0) EXTRACT8(zv1) EXTRACT8(zv2) EXTRACT8(zv3)
#undef EXTRACT8
        float tau = thr;
        if (__ballot(lc > 3) == 0ULL) {
            // fast path: <=3 candidates per lane (covers ~all rows on N(0,1)-like scores)
            #pragma unroll 1
            for (int it = 0; it < 24; ++it) {
                const float d0 = c0 - tau, d1 = c1 - tau, d2 = c2 - tau;
                float s = fmaxf(d0, 0.f) + fmaxf(d1, 0.f) + fmaxf(d2, 0.f);
                float c = (d0 > 0.f ? 1.f : 0.f) + (d1 > 0.f ? 1.f : 0.f) + (d2 > 0.f ? 1.f : 0.f);
                #pragma unroll
                for (int off = 32; off >= 1; off >>= 1) {
                    s += __shfl_xor(s, off);
                    c += __shfl_xor(c, off);
                }
                const float tn = tau + (s - 1.0f) / c;
                if (!(tn > tau)) break;       // support stable -> exact
                tau = tn;
            }
        } else {
            // rare fallback: full 32-elem Newton straight from the f16 registers
            #pragma unroll 1
            for (int it = 0; it < 32; ++it) {
                float s = 0.f, c = 0.f;
#define ACC8(ZV) { _Pragma("unroll") for (int e = 0; e < 8; ++e) { \
                const float d = (float)(ZV)[e] - tau; \
                s += fmaxf(d, 0.f); c += (d > 0.f ? 1.f : 0.f); } }
                ACC8(zv0) ACC8(zv1) ACC8(zv2) ACC8(zv3)
#undef ACC8
                #pragma unroll
                for (int off = 32; off >= 1; off >>= 1) {
                    s += __shfl_xor(s, off);
                    c += __shfl_xor(c, off);
                }
                const float tn = tau + (s - 1.0f) / c;
                if (!(tn > tau)) break;
                tau = tn;
            }
        }
        if (lane == 0) tau_s[w] = tau;
    }
    __syncthreads();

    // ---------------- Phase 3: out = P.V (MFMA); P = max(z - tau, 0) packed f16 --------
    const float tau_row = tau_s[row];
    f16x8 t8;
    {
        const _Float16 th = (_Float16)tau_row;
        #pragma unroll
        for (int e = 0; e < 8; ++e) t8[e] = th;
    }
    f32x4 o[4] = {{0.f,0.f,0.f,0.f},{0.f,0.f,0.f,0.f},{0.f,0.f,0.f,0.f},{0.f,0.f,0.f,0.f}};
    if constexpr (PRE) {
        // wave w covers k in [w*128, w*128+128): 4 chunks of 32 k x 64 d
        const _Float16* vsrc = Vt + bhSD + (size_t)w * 8192 + lane * 8;
        #pragma unroll
        for (int cl = 0; cl < 4; ++cl) {
            const int k0 = (w * 4 + cl) * 32;
            const f16x8 zv = *reinterpret_cast<const f16x8*>(
                &s_sh[row * 2048 + swz2(row, k0 + grp * 8)]);
            const f16x8 pa = __builtin_elementwise_max(zv - t8, (f16x8)(_Float16)0.0f);
            const f16x8 va0 = *reinterpret_cast<const f16x8*>(vsrc + cl * 2048);
            const f16x8 va1 = *reinterpret_cast<const f16x8*>(vsrc + cl * 2048 + 512);
            o[0] = __builtin_amdgcn_mfma_f32_16x16x32_f16(pa, va0, o[0], 0, 0, 0);
            o[1] = __builtin_amdgcn_mfma_f32_16x16x32_f16(pa, va1, o[1], 0, 0, 0);
            const f16x8 va2 = *reinterpret_cast<const f16x8*>(vsrc + cl * 2048 + 1024);
            const f16x8 va3 = *reinterpret_cast<const f16x8*>(vsrc + cl * 2048 + 1536);
            o[2] = __builtin_amdgcn_mfma_f32_16x16x32_f16(pa, va2, o[2], 0, 0, 0);
            o[3] = __builtin_amdgcn_mfma_f32_16x16x32_f16(pa, va3, o[3], 0, 0, 0);
        }
    } else {
        for (int c = w * 4; c < w * 4 + 4; ++c) {
            const int k0 = c * 32;
            const f16x8 zv = *reinterpret_cast<const f16x8*>(
                &s_sh[row * 2048 + swz2(row, k0 + grp * 8)]);
            const f16x8 pa2 = __builtin_elementwise_max(zv - t8, (f16x8)(_Float16)0.0f);
            #pragma unroll
            for (int n = 0; n < 4; ++n) {
                f16x8 vb;
                #pragma unroll
                for (int j = 0; j < 8; ++j)
                    vb[j] = (_Float16)V[bhSD + (size_t)(k0 + grp * 8 + j) * D + n * 16 + row];
                o[n] = __builtin_amdgcn_mfma_f32_16x16x32_f16(pa2, vb, o[n], 0, 0, 0);
            }
        }
    }

    // k-partial accumulation via LDS float atomics (pad 68 spreads banks; o[n][r] -> q=grp*4+r, d=n*16+row)
    #pragma unroll
    for (int n = 0; n < 4; ++n)
        #pragma unroll
        for (int r = 0; r < 4; ++r)
            atomicAdd(&red_sh[grp * 4 + r][n * 16 + row], o[n][r]);
    __syncthreads();

    {
        const int q = tid >> 6;               // 0..15
        const int d = tid & 63;               // 0..63
        out[bhSD + (size_t)(q0 + q) * D + d] = red_sh[q][d];
    }
}

extern "C" void kernel_launch(void* const* d_in, const int* in_sizes, int n_in,
                              void* d_out, int out_size, void* d_ws, size_t ws_size,
                              hipStream_t stream) {
    const float* Q     = (const float*)d_in[0];
    const float* K     = (const float*)d_in[1];
    const float* V     = (const float*)d_in[2];
    const float* mask  = (const float*)d_in[3];
    const float* scale = (const float*)d_in[4];
    float* out = (float*)d_out;

    const size_t need = 2 * BHSD * sizeof(_Float16);   // Kh + Vt = 12.6 MB
    if (ws_size >= need) {
        _Float16* Kh = (_Float16*)d_ws;
        _Float16* Vt = Kh + BHSD;
        cvt_k_kernel<<<dim3(B * H * 64), dim3(256), 0, stream>>>(K, Kh);
        tr_v_kernel<<<dim3(B * H * 64), dim3(256), 0, stream>>>(V, Vt);
        sparsemax_attn_kernel<true><<<dim3(B * H * NBLK_Q), dim3(1024), 0, stream>>>(
            Q, K, V, mask, scale, out, Kh, Vt);
    } else {
        sparsemax_attn_kernel<false><<<dim3(B * H * NBLK_Q), dim3(1024), 0, stream>>>(
            Q, K, V, mask, scale, out, nullptr, nullptr);
    }
}

// Round 9
// 245.674 us; speedup vs baseline: 1.5940x; 1.5940x over previous
//
#include <hip/hip_runtime.h>
#include <hip/hip_fp16.h>

constexpr int B = 2, H = 12, S = 2048, D = 64;
constexpr int TQ = 16;            // query rows per block
constexpr int NBLK_Q = S / TQ;    // 128
constexpr size_t BHSD = (size_t)B * H * S * D;   // 3,145,728

using f16x8 = _Float16 __attribute__((ext_vector_type(8)));
using f16x4 = _Float16 __attribute__((ext_vector_type(4)));
using f32x4 = float   __attribute__((ext_vector_type(4)));

// score swizzle: XOR element-index bits 3-5 with ((k>>6) ^ q). 4/8-granule preserving.
__device__ __forceinline__ int swz2(int q, int k) {
    return k ^ ((((k >> 6) ^ q) & 7) << 3);
}

// ---- pre-pass: K fp32 [bh][key][d] -> f16 MFMA-tiled ----
// Kh element index: t*1024 + c2*512 + (grp*16+row)*8 + e ; key=t*16+row, d=c2*32+grp*8+e
__global__ __launch_bounds__(256)
void cvt_k_kernel(const float* __restrict__ K, _Float16* __restrict__ Kh) {
    const int bh   = blockIdx.x >> 6;
    const int t    = (blockIdx.x & 63) * 2 + (threadIdx.x >> 7);
    const int f    = threadIdx.x & 127;           // c2*64 + grp*16 + row
    const int c2   = f >> 6, grp = (f >> 4) & 3, row = f & 15;
    const size_t bhSD = (size_t)bh * S * D;
    const float* src = K + bhSD + (size_t)(t * 16 + row) * D + c2 * 32 + grp * 8;
    const float4 x0 = *reinterpret_cast<const float4*>(src);
    const float4 x1 = *reinterpret_cast<const float4*>(src + 4);
    f16x8 y;
    y[0] = (_Float16)x0.x; y[1] = (_Float16)x0.y; y[2] = (_Float16)x0.z; y[3] = (_Float16)x0.w;
    y[4] = (_Float16)x1.x; y[5] = (_Float16)x1.y; y[6] = (_Float16)x1.z; y[7] = (_Float16)x1.w;
    *reinterpret_cast<f16x8*>(Kh + bhSD + (size_t)t * 1024 + f * 8) = y;
}

// ---- pre-pass: V fp32 [bh][k][d] -> f16 MFMA-tiled transposed ----
// Vt element index: c*2048 + dh*1024 + n2*512 + (grp*16+row)*8 + e ; d=dh*32+n2*16+row, k=c*32+grp*8+e
__global__ __launch_bounds__(256)
void tr_v_kernel(const float* __restrict__ V, _Float16* __restrict__ Vt) {
    const int bh = blockIdx.x >> 6;
    const int c  = blockIdx.x & 63;
    const int f  = threadIdx.x;                   // dh*128 + n2*64 + grp*16 + row
    const int dh = f >> 7, n2 = (f >> 6) & 1, grp = (f >> 4) & 3, row = f & 15;
    const int d  = dh * 32 + n2 * 16 + row;
    const size_t bhSD = (size_t)bh * S * D;
    const float* src = V + bhSD + (size_t)(c * 32 + grp * 8) * D + d;
    f16x8 y;
    #pragma unroll
    for (int e = 0; e < 8; ++e) y[e] = (_Float16)src[e * D];
    *reinterpret_cast<f16x8*>(Vt + bhSD + (size_t)c * 2048 + f * 8) = y;
}

// ---------------- main fused kernel: 512 threads / 8 waves, 2 blocks/CU, no spill ----------------
template <bool PRE>
__global__ __launch_bounds__(512, 4)
void sparsemax_attn_kernel(const float* __restrict__ Q, const float* __restrict__ K,
                           const float* __restrict__ V, const float* __restrict__ mask,
                           const float* __restrict__ scale, float* __restrict__ out,
                           const _Float16* __restrict__ Kh, const _Float16* __restrict__ Vt)
{
    __shared__ alignas(16) _Float16 s_sh[TQ * 2048];      // 64 KB scores [q][k-swz]
    __shared__ alignas(16) float    madd_sh[S];           // 8 KB mask additive terms
    __shared__ alignas(16) float    red_sh[TQ][68];       // 4.25 KB output accumulators (padded)
    __shared__ float tau_s[TQ];

    const int tid  = threadIdx.x;
    const int lane = tid & 63;
    const int w    = tid >> 6;              // wave 0..7
    const int row  = lane & 15;
    const int grp  = lane >> 4;             // 0..3
    const int bh   = blockIdx.x / NBLK_Q;
    const int qt   = blockIdx.x - bh * NBLK_Q;
    const int b    = bh / H;
    const int h    = bh - b * H;
    const int q0   = qt * TQ;

    const size_t bhSD = (size_t)bh * S * D;
    const float* mrow = mask + (size_t)b * S;
    const float  sc   = __expf(scale[h]) * 0.125f;

    // mask -> LDS additive terms (4 per thread); zero the output accumulators
    #pragma unroll
    for (int i = 0; i < 4; ++i)
        madd_sh[tid + i * 512] = (1.0f - mrow[tid + i * 512]) * -1.0e9f;
    reinterpret_cast<float*>(red_sh)[tid]       = 0.0f;
    reinterpret_cast<float*>(red_sh)[tid + 512] = 0.0f;
    if (tid < TQ * 68 - 1024) reinterpret_cast<float*>(red_sh)[tid + 1024] = 0.0f;

    // ---- Q fragments, sc folded in: qa[c][j] = Q[q0+row][c*32+grp*8+j] * sc ----
    f16x8 qa[2];
    {
        const float* qr = Q + bhSD + (size_t)(q0 + row) * D + grp * 8;
        #pragma unroll
        for (int c = 0; c < 2; ++c) {
            const float4 x0 = *reinterpret_cast<const float4*>(qr + c * 32);
            const float4 x1 = *reinterpret_cast<const float4*>(qr + c * 32 + 4);
            qa[c][0] = (_Float16)(x0.x * sc); qa[c][1] = (_Float16)(x0.y * sc);
            qa[c][2] = (_Float16)(x0.z * sc); qa[c][3] = (_Float16)(x0.w * sc);
            qa[c][4] = (_Float16)(x1.x * sc); qa[c][5] = (_Float16)(x1.y * sc);
            qa[c][6] = (_Float16)(x1.z * sc); qa[c][7] = (_Float16)(x1.w * sc);
        }
    }
    __syncthreads();   // madd + red init visible

    // ---------------- Phase 1: S^T tiles via mfma(K, Q) -> [q][k] LDS ----------------
    // wave w owns key-tiles w*16 .. w*16+15; fragment = bytes lane*16 of each 1 KB tile.
    if constexpr (PRE) {
        const _Float16* ksrc = Kh + bhSD + (size_t)(w * 16) * 1024 + lane * 8;
        f16x8 ka0 = *reinterpret_cast<const f16x8*>(ksrc);
        f16x8 ka1 = *reinterpret_cast<const f16x8*>(ksrc + 512);
        #pragma unroll
        for (int i = 0; i < 16; ++i) {
            f16x8 nb0, nb1;
            if (i < 15) {
                nb0 = *reinterpret_cast<const f16x8*>(ksrc + (i + 1) * 1024);
                nb1 = *reinterpret_cast<const f16x8*>(ksrc + (i + 1) * 1024 + 512);
            }
            f32x4 acc = {0.f, 0.f, 0.f, 0.f};
            acc = __builtin_amdgcn_mfma_f32_16x16x32_f16(ka0, qa[0], acc, 0, 0, 0);
            acc = __builtin_amdgcn_mfma_f32_16x16x32_f16(ka1, qa[1], acc, 0, 0, 0);
            const int key0 = (w * 16 + i) * 16;
            const float4 ma = *reinterpret_cast<const float4*>(madd_sh + key0 + grp * 4);
            f16x4 st;
            #pragma unroll
            for (int r = 0; r < 4; ++r)
                st[r] = (_Float16)fmaxf(acc[r] + (&ma.x)[r], -60000.0f);
            *reinterpret_cast<f16x4*>(&s_sh[row * 2048 + swz2(row, key0 + grp * 4)]) = st;
            ka0 = nb0; ka1 = nb1;
        }
    } else {
        for (int t = w * 16; t < w * 16 + 16; ++t) {
            const int key0 = t * 16;
            const float* kp = K + bhSD + (size_t)(key0 + row) * D + grp * 8;
            f16x8 kb0, kb1;
            #pragma unroll
            for (int c = 0; c < 2; ++c) {
                const float4 x0 = *reinterpret_cast<const float4*>(kp + c * 32);
                const float4 x1 = *reinterpret_cast<const float4*>(kp + c * 32 + 4);
                f16x8& kb = c ? kb1 : kb0;
                kb[0] = (_Float16)x0.x; kb[1] = (_Float16)x0.y;
                kb[2] = (_Float16)x0.z; kb[3] = (_Float16)x0.w;
                kb[4] = (_Float16)x1.x; kb[5] = (_Float16)x1.y;
                kb[6] = (_Float16)x1.z; kb[7] = (_Float16)x1.w;
            }
            f32x4 acc = {0.f, 0.f, 0.f, 0.f};
            acc = __builtin_amdgcn_mfma_f32_16x16x32_f16(kb0, qa[0], acc, 0, 0, 0);
            acc = __builtin_amdgcn_mfma_f32_16x16x32_f16(kb1, qa[1], acc, 0, 0, 0);
            const float4 ma = *reinterpret_cast<const float4*>(madd_sh + key0 + grp * 4);
            f16x4 st;
            #pragma unroll
            for (int r = 0; r < 4; ++r)
                st[r] = (_Float16)fmaxf(acc[r] + (&ma.x)[r], -60000.0f);
            *reinterpret_cast<f16x4*>(&s_sh[row * 2048 + swz2(row, key0 + grp * 4)]) = st;
        }
    }
    __syncthreads();

    // ---------------- Phase 2: tau for rows q = 2w, 2w+1 (register-resident) ----------
    #pragma unroll 1
    for (int rr = 0; rr < 2; ++rr) {
        const int q = w * 2 + rr;
        const _Float16* zrow = &s_sh[q * 2048];
        const f16x8 zv0 = *reinterpret_cast<const f16x8*>(&zrow[swz2(q, lane * 32 +  0)]);
        const f16x8 zv1 = *reinterpret_cast<const f16x8*>(&zrow[swz2(q, lane * 32 +  8)]);
        const f16x8 zv2 = *reinterpret_cast<const f16x8*>(&zrow[swz2(q, lane * 32 + 16)]);
        const f16x8 zv3 = *reinterpret_cast<const f16x8*>(&zrow[swz2(q, lane * 32 + 24)]);
        const f16x8 m8 = __builtin_elementwise_max(__builtin_elementwise_max(zv0, zv1),
                                                   __builtin_elementwise_max(zv2, zv3));
        float m = (float)m8[0];
        #pragma unroll
        for (int e = 1; e < 8; ++e) m = fmaxf(m, (float)m8[e]);
        #pragma unroll
        for (int off = 32; off >= 1; off >>= 1) m = fmaxf(m, __shfl_xor(m, off));
        const float thr = m - 1.0f;          // tau* >= max-1
        float c0 = -1.0e30f, c1 = -1.0e30f, c2 = -1.0e30f;
        int lc = 0;
#define EXTRACT8(ZV) { _Pragma("unroll") for (int e = 0; e < 8; ++e) { \
            const float zz = (float)(ZV)[e]; \
            if (zz > thr) { \
                c2 = (lc == 2) ? zz : c2; \
                c1 = (lc == 1) ? zz : c1; \
                c0 = (lc == 0) ? zz : c0; \
                ++lc; } } }
        EXTRACT8(zv0) EXTRACT8(zv1) EXTRACT8(zv2) EXTRACT8(zv3)
#undef EXTRACT8
        float tau = thr;
        if (__ballot(lc > 3) == 0ULL) {
            // fast path: <=3 candidates per lane (covers ~all rows on N(0,1)-like scores)
            #pragma unroll 1
            for (int it = 0; it < 24; ++it) {
                const float d0 = c0 - tau, d1 = c1 - tau, d2 = c2 - tau;
                float s = fmaxf(d0, 0.f) + fmaxf(d1, 0.f) + fmaxf(d2, 0.f);
                float c = (d0 > 0.f ? 1.f : 0.f) + (d1 > 0.f ? 1.f : 0.f) + (d2 > 0.f ? 1.f : 0.f);
                #pragma unroll
                for (int off = 32; off >= 1; off >>= 1) {
                    s += __shfl_xor(s, off);
                    c += __shfl_xor(c, off);
                }
                const float tn = tau + (s - 1.0f) / c;
                if (!(tn > tau)) break;       // support stable -> exact
                tau = tn;
            }
        } else {
            // rare fallback: full 32-elem Newton straight from the f16 registers
            #pragma unroll 1
            for (int it = 0; it < 32; ++it) {
                float s = 0.f, c = 0.f;
#define ACC8(ZV) { _Pragma("unroll") for (int e = 0; e < 8; ++e) { \
                const float d = (float)(ZV)[e] - tau; \
                s += fmaxf(d, 0.f); c += (d > 0.f ? 1.f : 0.f); } }
                ACC8(zv0) ACC8(zv1) ACC8(zv2) ACC8(zv3)
#undef ACC8
                #pragma unroll
                for (int off = 32; off >= 1; off >>= 1) {
                    s += __shfl_xor(s, off);
                    c += __shfl_xor(c, off);
                }
                const float tn = tau + (s - 1.0f) / c;
                if (!(tn > tau)) break;
                tau = tn;
            }
        }
        if (lane == 0) tau_s[q] = tau;
    }
    __syncthreads();

    // ---------------- Phase 3: out = P.V (MFMA); P = max(z - tau, 0) packed f16 --------
    const float tau_row = tau_s[row];
    f16x8 t8;
    {
        const _Float16 th = (_Float16)tau_row;
        #pragma unroll
        for (int e = 0; e < 8; ++e) t8[e] = th;
    }
    f32x4 o[4] = {{0.f,0.f,0.f,0.f},{0.f,0.f,0.f,0.f},{0.f,0.f,0.f,0.f},{0.f,0.f,0.f,0.f}};
    if constexpr (PRE) {
        // wave w covers k in [w*256, w*256+256): 8 chunks of 32 k x 64 d
        const _Float16* vsrc = Vt + bhSD + (size_t)w * 16384 + lane * 8;
        #pragma unroll
        for (int cl = 0; cl < 8; ++cl) {
            const int k0 = (w * 8 + cl) * 32;
            const f16x8 zv = *reinterpret_cast<const f16x8*>(
                &s_sh[row * 2048 + swz2(row, k0 + grp * 8)]);
            const f16x8 pa = __builtin_elementwise_max(zv - t8, (f16x8)(_Float16)0.0f);
            const f16x8 va0 = *reinterpret_cast<const f16x8*>(vsrc + cl * 2048);
            const f16x8 va1 = *reinterpret_cast<const f16x8*>(vsrc + cl * 2048 + 512);
            o[0] = __builtin_amdgcn_mfma_f32_16x16x32_f16(pa, va0, o[0], 0, 0, 0);
            o[1] = __builtin_amdgcn_mfma_f32_16x16x32_f16(pa, va1, o[1], 0, 0, 0);
            const f16x8 va2 = *reinterpret_cast<const f16x8*>(vsrc + cl * 2048 + 1024);
            const f16x8 va3 = *reinterpret_cast<const f16x8*>(vsrc + cl * 2048 + 1536);
            o[2] = __builtin_amdgcn_mfma_f32_16x16x32_f16(pa, va2, o[2], 0, 0, 0);
            o[3] = __builtin_amdgcn_mfma_f32_16x16x32_f16(pa, va3, o[3], 0, 0, 0);
        }
    } else {
        for (int c = w * 8; c < w * 8 + 8; ++c) {
            const int k0 = c * 32;
            const f16x8 zv = *reinterpret_cast<const f16x8*>(
                &s_sh[row * 2048 + swz2(row, k0 + grp * 8)]);
            const f16x8 pa2 = __builtin_elementwise_max(zv - t8, (f16x8)(_Float16)0.0f);
            #pragma unroll
            for (int n = 0; n < 4; ++n) {
                f16x8 vb;
                #pragma unroll
                for (int j = 0; j < 8; ++j)
                    vb[j] = (_Float16)V[bhSD + (size_t)(k0 + grp * 8 + j) * D + n * 16 + row];
                o[n] = __builtin_amdgcn_mfma_f32_16x16x32_f16(pa2, vb, o[n], 0, 0, 0);
            }
        }
    }

    // k-partial accumulation via LDS float atomics (o[n][r] -> q=grp*4+r, d=n*16+row)
    #pragma unroll
    for (int n = 0; n < 4; ++n)
        #pragma unroll
        for (int r = 0; r < 4; ++r)
            atomicAdd(&red_sh[grp * 4 + r][n * 16 + row], o[n][r]);
    __syncthreads();

    {
        #pragma unroll
        for (int i = 0; i < 2; ++i) {
            const int idx = tid + i * 512;
            const int q = idx >> 6;           // 0..15
            const int d = idx & 63;           // 0..63
            out[bhSD + (size_t)(q0 + q) * D + d] = red_sh[q][d];
        }
    }
}

extern "C" void kernel_launch(void* const* d_in, const int* in_sizes, int n_in,
                              void* d_out, int out_size, void* d_ws, size_t ws_size,
                              hipStream_t stream) {
    const float* Q     = (const float*)d_in[0];
    const float* K     = (const float*)d_in[1];
    const float* V     = (const float*)d_in[2];
    const float* mask  = (const float*)d_in[3];
    const float* scale = (const float*)d_in[4];
    float* out = (float*)d_out;

    const size_t need = 2 * BHSD * sizeof(_Float16);   // Kh + Vt = 12.6 MB
    if (ws_size >= need) {
        _Float16* Kh = (_Float16*)d_ws;
        _Float16* Vt = Kh + BHSD;
        cvt_k_kernel<<<dim3(B * H * 64), dim3(256), 0, stream>>>(K, Kh);
        tr_v_kernel<<<dim3(B * H * 64), dim3(256), 0, stream>>>(V, Vt);
        sparsemax_attn_kernel<true><<<dim3(B * H * NBLK_Q), dim3(512), 0, stream>>>(
            Q, K, V, mask, scale, out, Kh, Vt);
    } else {
        sparsemax_attn_kernel<false><<<dim3(B * H * NBLK_Q), dim3(512), 0, stream>>>(
            Q, K, V, mask, scale, out, nullptr, nullptr);
    }
}